// Round 5
// baseline (152.342 us; speedup 1.0000x reference)
//
#include <hip/hip_runtime.h>
#include <hip/hip_bf16.h>

// InferenceLinear: out[m][n] = sum_k x[m][k] * (q[n][k]*qrange[n][k/256] + qmin[n][k/256])
// M=512, N=2048, K=4096, 16 groups of 256.
// R5: KSPLIT=8 occupancy (8 blocks/CU) kept, but atomics replaced with
// deterministic ws-partials + reduction kernel (R4 showed atomics caused
// 350 MB of HBM RMW traffic). Fallback to KSPLIT=4 atomics if ws too small.
// BM=BN=BK=64, 256 threads (4 waves 2x2, each wave 32x32 via 2x2 16x16x32 frags).

#define M_T 512
#define N_T 2048
#define K_T 4096
#define NGRP 16
#define BM 64
#define BN 64
#define BK 64
#define OUT_ELEMS (M_T * N_T)

typedef __attribute__((ext_vector_type(8))) short mfrag_t;           // 8 bf16 (4 VGPR)
typedef __attribute__((ext_vector_type(8))) unsigned short u16x8;
typedef __attribute__((ext_vector_type(4))) float f32x4;

__device__ __forceinline__ unsigned short f2bf(float f) {
  union { __hip_bfloat16 h; unsigned short u; } c;
  c.h = __float2bfloat16(f);
  return c.u;
}

// ATOMIC=false: write fp32 partial to ws slice (dst = ws + kc*OUT_ELEMS)
// ATOMIC=true : atomicAdd into dst (= out, pre-zeroed)
template <int KSPLIT, bool ATOMIC>
__global__ __launch_bounds__(256, 8) void dq_gemm_kernel(
    const float* __restrict__ x, const int* __restrict__ qw,
    const float* __restrict__ qrange, const float* __restrict__ qmin,
    float* __restrict__ dst) {
  constexpr int KC = K_T / KSPLIT;
  constexpr int NTC = KC / BK;

  // single-buffered, swizzled [row][slot^(row&7)] storage, 8-elem (16B) slots
  __shared__ __align__(16) unsigned short As[BM * BK];
  __shared__ __align__(16) unsigned short Bs[BM * BK];

  const int tid = threadIdx.x;
  const int n0 = blockIdx.x * BN;
  const int m0 = blockIdx.y * BM;
  const int kc = blockIdx.z;        // k-chunk index
  const int kbase = kc * KC;

  // staging mapping: thread -> (row, 16-elem segment)
  const int srow = tid >> 2;   // 0..63
  const int sseg = tid & 3;    // 0..3

  const float* xp = x + (size_t)(m0 + srow) * K_T + kbase + sseg * 16;
  const int* qp = qw + (size_t)(n0 + srow) * K_T + kbase + sseg * 16;
  const float* qrp = qrange + (size_t)(n0 + srow) * NGRP;
  const float* qmp = qmin + (size_t)(n0 + srow) * NGRP;

  // compute mapping
  const int lane = tid & 63;
  const int wv = tid >> 6;
  const int wm = (wv >> 1) * 32;
  const int wn = (wv & 1) * 32;
  const int lr = lane & 15;    // row/col within fragment
  const int lq = lane >> 4;    // 0..3 -> k chunk

  float4 av[4];
  int4 qv[4];
  float sc, mn;

  // prologue loads (t=0)
  {
    const float* a = xp;
    av[0] = *(const float4*)(a + 0);
    av[1] = *(const float4*)(a + 4);
    av[2] = *(const float4*)(a + 8);
    av[3] = *(const float4*)(a + 12);
    const int4* q = (const int4*)qp;
    qv[0] = q[0]; qv[1] = q[1]; qv[2] = q[2]; qv[3] = q[3];
    sc = qrp[kc * (KC / 256)];
    mn = qmp[kc * (KC / 256)];
  }

  f32x4 acc[2][2] = {};

  const int rx7 = srow & 7;
  const int abase = srow * BK;
  const int wslot0 = ((sseg * 2) ^ rx7) << 3;
  const int wslot1 = ((sseg * 2 + 1) ^ rx7) << 3;
  const int rxl = lr & 7;  // read-side xor

  for (int t = 0; t < NTC; ++t) {
    if (t > 0) __syncthreads();  // previous compute done before LDS overwrite

    // ---- stage regs -> LDS (convert to bf16 / dequant) ----
    {
      u16x8 pa0, pa1, pb0, pb1;
      pa0[0] = f2bf(av[0].x); pa0[1] = f2bf(av[0].y); pa0[2] = f2bf(av[0].z); pa0[3] = f2bf(av[0].w);
      pa0[4] = f2bf(av[1].x); pa0[5] = f2bf(av[1].y); pa0[6] = f2bf(av[1].z); pa0[7] = f2bf(av[1].w);
      pa1[0] = f2bf(av[2].x); pa1[1] = f2bf(av[2].y); pa1[2] = f2bf(av[2].z); pa1[3] = f2bf(av[2].w);
      pa1[4] = f2bf(av[3].x); pa1[5] = f2bf(av[3].y); pa1[6] = f2bf(av[3].z); pa1[7] = f2bf(av[3].w);
      pb0[0] = f2bf((float)qv[0].x * sc + mn); pb0[1] = f2bf((float)qv[0].y * sc + mn);
      pb0[2] = f2bf((float)qv[0].z * sc + mn); pb0[3] = f2bf((float)qv[0].w * sc + mn);
      pb0[4] = f2bf((float)qv[1].x * sc + mn); pb0[5] = f2bf((float)qv[1].y * sc + mn);
      pb0[6] = f2bf((float)qv[1].z * sc + mn); pb0[7] = f2bf((float)qv[1].w * sc + mn);
      pb1[0] = f2bf((float)qv[2].x * sc + mn); pb1[1] = f2bf((float)qv[2].y * sc + mn);
      pb1[2] = f2bf((float)qv[2].z * sc + mn); pb1[3] = f2bf((float)qv[2].w * sc + mn);
      pb1[4] = f2bf((float)qv[3].x * sc + mn); pb1[5] = f2bf((float)qv[3].y * sc + mn);
      pb1[6] = f2bf((float)qv[3].z * sc + mn); pb1[7] = f2bf((float)qv[3].w * sc + mn);
      *(u16x8*)&As[abase + wslot0] = pa0;
      *(u16x8*)&As[abase + wslot1] = pa1;
      *(u16x8*)&Bs[abase + wslot0] = pb0;
      *(u16x8*)&Bs[abase + wslot1] = pb1;
    }

    // ---- issue next tile's global loads (complete during compute phase) ----
    if (t + 1 < NTC) {
      const float* a = xp + (size_t)(t + 1) * BK;
      av[0] = *(const float4*)(a + 0);
      av[1] = *(const float4*)(a + 4);
      av[2] = *(const float4*)(a + 8);
      av[3] = *(const float4*)(a + 12);
      const int4* q = (const int4*)(qp + (size_t)(t + 1) * BK);
      qv[0] = q[0]; qv[1] = q[1]; qv[2] = q[2]; qv[3] = q[3];
      const int g = kc * (KC / 256) + ((t + 1) >> 2);  // group = 4 tiles of 64
      sc = qrp[g];
      mn = qmp[g];
    }

    __syncthreads();

    // ---- compute tile t: 2 K-substeps of 32, 2x2 fragments ----
#pragma unroll
    for (int kk = 0; kk < 2; ++kk) {
      const int so = ((kk * 4 + lq) ^ rxl) << 3;
      mfrag_t af0 = *(const mfrag_t*)&As[(wm + lr) * BK + so];
      mfrag_t af1 = *(const mfrag_t*)&As[(wm + 16 + lr) * BK + so];
      mfrag_t bf0 = *(const mfrag_t*)&Bs[(wn + lr) * BK + so];
      mfrag_t bf1 = *(const mfrag_t*)&Bs[(wn + 16 + lr) * BK + so];
      acc[0][0] = __builtin_amdgcn_mfma_f32_16x16x32_bf16(af0, bf0, acc[0][0], 0, 0, 0);
      acc[0][1] = __builtin_amdgcn_mfma_f32_16x16x32_bf16(af0, bf1, acc[0][1], 0, 0, 0);
      acc[1][0] = __builtin_amdgcn_mfma_f32_16x16x32_bf16(af1, bf0, acc[1][0], 0, 0, 0);
      acc[1][1] = __builtin_amdgcn_mfma_f32_16x16x32_bf16(af1, bf1, acc[1][1], 0, 0, 0);
    }
  }

  // ---- epilogue. C/D layout col=lane&15, row=(lane>>4)*4+reg ----
  float* base = ATOMIC ? dst : dst + (size_t)kc * OUT_ELEMS;
#pragma unroll
  for (int fm = 0; fm < 2; ++fm) {
#pragma unroll
    for (int fn = 0; fn < 2; ++fn) {
      const int r0 = m0 + wm + fm * 16 + lq * 4;
      const int c = n0 + wn + fn * 16 + lr;
      float* op = base + (size_t)r0 * N_T + c;
      if (ATOMIC) {
        atomicAdd(&op[0 * (size_t)N_T], acc[fm][fn][0]);
        atomicAdd(&op[1 * (size_t)N_T], acc[fm][fn][1]);
        atomicAdd(&op[2 * (size_t)N_T], acc[fm][fn][2]);
        atomicAdd(&op[3 * (size_t)N_T], acc[fm][fn][3]);
      } else {
        op[0 * (size_t)N_T] = acc[fm][fn][0];
        op[1 * (size_t)N_T] = acc[fm][fn][1];
        op[2 * (size_t)N_T] = acc[fm][fn][2];
        op[3 * (size_t)N_T] = acc[fm][fn][3];
      }
    }
  }
}

// out[i] = sum_s ws[s*OUT_ELEMS + i], vectorized float4, fixed order (deterministic)
template <int KSPLIT>
__global__ __launch_bounds__(256) void reduce_kernel(const float* __restrict__ ws,
                                                     float* __restrict__ out) {
  const int i4 = blockIdx.x * 256 + threadIdx.x;
  const size_t base = (size_t)i4 * 4;
  float4 a = *(const float4*)(ws + base);
#pragma unroll
  for (int s = 1; s < KSPLIT; ++s) {
    float4 b = *(const float4*)(ws + (size_t)s * OUT_ELEMS + base);
    a.x += b.x; a.y += b.y; a.z += b.z; a.w += b.w;
  }
  *(float4*)(out + base) = a;
}

extern "C" void kernel_launch(void* const* d_in, const int* in_sizes, int n_in,
                              void* d_out, int out_size, void* d_ws, size_t ws_size,
                              hipStream_t stream) {
  const float* x = (const float*)d_in[0];
  const int* qw = (const int*)d_in[1];
  const float* qr = (const float*)d_in[2];
  const float* qm = (const float*)d_in[3];
  float* out = (float*)d_out;
  float* ws = (float*)d_ws;

  constexpr int KS = 8;
  const size_t need = (size_t)KS * OUT_ELEMS * sizeof(float);
  if (ws_size >= need) {
    dim3 grid(N_T / BN, M_T / BM, KS);
    dq_gemm_kernel<KS, false><<<grid, dim3(256, 1, 1), 0, stream>>>(x, qw, qr, qm, ws);
    reduce_kernel<KS><<<OUT_ELEMS / 4 / 256, 256, 0, stream>>>(ws, out);
  } else {
    // fallback: known-good R2 path (KSPLIT=4, atomics into zeroed out)
    hipMemsetAsync(out, 0, (size_t)OUT_ELEMS * sizeof(float), stream);
    dim3 grid(N_T / BN, M_T / BM, 4);
    dq_gemm_kernel<4, true><<<grid, dim3(256, 1, 1), 0, stream>>>(x, qw, qr, qm, out);
  }
}

// Round 6
// 50.765 us; speedup vs baseline: 3.0009x; 3.0009x over previous
//
#include <hip/hip_runtime.h>
#include <hip/hip_bf16.h>

// InferenceLinear: out[m][n] = sum_k x[m][k] * (q[n][k]*qrange[n][k/256] + qmin[n][k/256])
// M=512, N=2048, K=4096, 16 groups of 256.
// R6: same as R5 (KSPLIT=8, ws partials + deterministic reduce) but
// __launch_bounds__(256,4): R4/R5's launch_bounds(256,8) forced 32 VGPRs ->
// scratch spills -> 200-330MB of HBM spill traffic. 128-reg budget removes spills
// (R2 control: 44 VGPRs, FETCH=49MB exactly compulsory).
// BM=BN=BK=64, 256 threads (4 waves 2x2, each wave 32x32 via 2x2 16x16x32 frags).

#define M_T 512
#define N_T 2048
#define K_T 4096
#define NGRP 16
#define BM 64
#define BN 64
#define BK 64
#define OUT_ELEMS (M_T * N_T)

typedef __attribute__((ext_vector_type(8))) short mfrag_t;           // 8 bf16 (4 VGPR)
typedef __attribute__((ext_vector_type(8))) unsigned short u16x8;
typedef __attribute__((ext_vector_type(4))) float f32x4;

__device__ __forceinline__ unsigned short f2bf(float f) {
  union { __hip_bfloat16 h; unsigned short u; } c;
  c.h = __float2bfloat16(f);
  return c.u;
}

// ATOMIC=false: write fp32 partial to ws slice (dst = ws + kc*OUT_ELEMS)
// ATOMIC=true : atomicAdd into dst (= out, pre-zeroed)
template <int KSPLIT, bool ATOMIC>
__global__ __launch_bounds__(256, 4) void dq_gemm_kernel(
    const float* __restrict__ x, const int* __restrict__ qw,
    const float* __restrict__ qrange, const float* __restrict__ qmin,
    float* __restrict__ dst) {
  constexpr int KC = K_T / KSPLIT;
  constexpr int NTC = KC / BK;

  // single-buffered, swizzled [row][slot^(row&7)] storage, 8-elem (16B) slots
  __shared__ __align__(16) unsigned short As[BM * BK];
  __shared__ __align__(16) unsigned short Bs[BM * BK];

  const int tid = threadIdx.x;
  const int n0 = blockIdx.x * BN;
  const int m0 = blockIdx.y * BM;
  const int kc = blockIdx.z;        // k-chunk index
  const int kbase = kc * KC;

  // staging mapping: thread -> (row, 16-elem segment)
  const int srow = tid >> 2;   // 0..63
  const int sseg = tid & 3;    // 0..3

  const float* xp = x + (size_t)(m0 + srow) * K_T + kbase + sseg * 16;
  const int* qp = qw + (size_t)(n0 + srow) * K_T + kbase + sseg * 16;
  const float* qrp = qrange + (size_t)(n0 + srow) * NGRP;
  const float* qmp = qmin + (size_t)(n0 + srow) * NGRP;

  // compute mapping
  const int lane = tid & 63;
  const int wv = tid >> 6;
  const int wm = (wv >> 1) * 32;
  const int wn = (wv & 1) * 32;
  const int lr = lane & 15;    // row/col within fragment
  const int lq = lane >> 4;    // 0..3 -> k chunk

  float4 av[4];
  int4 qv[4];
  float sc, mn;

  // prologue loads (t=0)
  {
    const float* a = xp;
    av[0] = *(const float4*)(a + 0);
    av[1] = *(const float4*)(a + 4);
    av[2] = *(const float4*)(a + 8);
    av[3] = *(const float4*)(a + 12);
    const int4* q = (const int4*)qp;
    qv[0] = q[0]; qv[1] = q[1]; qv[2] = q[2]; qv[3] = q[3];
    sc = qrp[kc * (KC / 256)];
    mn = qmp[kc * (KC / 256)];
  }

  f32x4 acc[2][2] = {};

  const int rx7 = srow & 7;
  const int abase = srow * BK;
  const int wslot0 = ((sseg * 2) ^ rx7) << 3;
  const int wslot1 = ((sseg * 2 + 1) ^ rx7) << 3;
  const int rxl = lr & 7;  // read-side xor

  for (int t = 0; t < NTC; ++t) {
    if (t > 0) __syncthreads();  // previous compute done before LDS overwrite

    // ---- stage regs -> LDS (convert to bf16 / dequant) ----
    {
      u16x8 pa0, pa1, pb0, pb1;
      pa0[0] = f2bf(av[0].x); pa0[1] = f2bf(av[0].y); pa0[2] = f2bf(av[0].z); pa0[3] = f2bf(av[0].w);
      pa0[4] = f2bf(av[1].x); pa0[5] = f2bf(av[1].y); pa0[6] = f2bf(av[1].z); pa0[7] = f2bf(av[1].w);
      pa1[0] = f2bf(av[2].x); pa1[1] = f2bf(av[2].y); pa1[2] = f2bf(av[2].z); pa1[3] = f2bf(av[2].w);
      pa1[4] = f2bf(av[3].x); pa1[5] = f2bf(av[3].y); pa1[6] = f2bf(av[3].z); pa1[7] = f2bf(av[3].w);
      pb0[0] = f2bf((float)qv[0].x * sc + mn); pb0[1] = f2bf((float)qv[0].y * sc + mn);
      pb0[2] = f2bf((float)qv[0].z * sc + mn); pb0[3] = f2bf((float)qv[0].w * sc + mn);
      pb0[4] = f2bf((float)qv[1].x * sc + mn); pb0[5] = f2bf((float)qv[1].y * sc + mn);
      pb0[6] = f2bf((float)qv[1].z * sc + mn); pb0[7] = f2bf((float)qv[1].w * sc + mn);
      pb1[0] = f2bf((float)qv[2].x * sc + mn); pb1[1] = f2bf((float)qv[2].y * sc + mn);
      pb1[2] = f2bf((float)qv[2].z * sc + mn); pb1[3] = f2bf((float)qv[2].w * sc + mn);
      pb1[4] = f2bf((float)qv[3].x * sc + mn); pb1[5] = f2bf((float)qv[3].y * sc + mn);
      pb1[6] = f2bf((float)qv[3].z * sc + mn); pb1[7] = f2bf((float)qv[3].w * sc + mn);
      *(u16x8*)&As[abase + wslot0] = pa0;
      *(u16x8*)&As[abase + wslot1] = pa1;
      *(u16x8*)&Bs[abase + wslot0] = pb0;
      *(u16x8*)&Bs[abase + wslot1] = pb1;
    }

    // ---- issue next tile's global loads (complete during compute phase) ----
    if (t + 1 < NTC) {
      const float* a = xp + (size_t)(t + 1) * BK;
      av[0] = *(const float4*)(a + 0);
      av[1] = *(const float4*)(a + 4);
      av[2] = *(const float4*)(a + 8);
      av[3] = *(const float4*)(a + 12);
      const int4* q = (const int4*)(qp + (size_t)(t + 1) * BK);
      qv[0] = q[0]; qv[1] = q[1]; qv[2] = q[2]; qv[3] = q[3];
      const int g = kc * (KC / 256) + ((t + 1) >> 2);  // group = 4 tiles of 64
      sc = qrp[g];
      mn = qmp[g];
    }

    __syncthreads();

    // ---- compute tile t: 2 K-substeps of 32, 2x2 fragments ----
#pragma unroll
    for (int kk = 0; kk < 2; ++kk) {
      const int so = ((kk * 4 + lq) ^ rxl) << 3;
      mfrag_t af0 = *(const mfrag_t*)&As[(wm + lr) * BK + so];
      mfrag_t af1 = *(const mfrag_t*)&As[(wm + 16 + lr) * BK + so];
      mfrag_t bf0 = *(const mfrag_t*)&Bs[(wn + lr) * BK + so];
      mfrag_t bf1 = *(const mfrag_t*)&Bs[(wn + 16 + lr) * BK + so];
      acc[0][0] = __builtin_amdgcn_mfma_f32_16x16x32_bf16(af0, bf0, acc[0][0], 0, 0, 0);
      acc[0][1] = __builtin_amdgcn_mfma_f32_16x16x32_bf16(af0, bf1, acc[0][1], 0, 0, 0);
      acc[1][0] = __builtin_amdgcn_mfma_f32_16x16x32_bf16(af1, bf0, acc[1][0], 0, 0, 0);
      acc[1][1] = __builtin_amdgcn_mfma_f32_16x16x32_bf16(af1, bf1, acc[1][1], 0, 0, 0);
    }
  }

  // ---- epilogue. C/D layout col=lane&15, row=(lane>>4)*4+reg ----
  float* base = ATOMIC ? dst : dst + (size_t)kc * OUT_ELEMS;
#pragma unroll
  for (int fm = 0; fm < 2; ++fm) {
#pragma unroll
    for (int fn = 0; fn < 2; ++fn) {
      const int r0 = m0 + wm + fm * 16 + lq * 4;
      const int c = n0 + wn + fn * 16 + lr;
      float* op = base + (size_t)r0 * N_T + c;
      if (ATOMIC) {
        atomicAdd(&op[0 * (size_t)N_T], acc[fm][fn][0]);
        atomicAdd(&op[1 * (size_t)N_T], acc[fm][fn][1]);
        atomicAdd(&op[2 * (size_t)N_T], acc[fm][fn][2]);
        atomicAdd(&op[3 * (size_t)N_T], acc[fm][fn][3]);
      } else {
        op[0 * (size_t)N_T] = acc[fm][fn][0];
        op[1 * (size_t)N_T] = acc[fm][fn][1];
        op[2 * (size_t)N_T] = acc[fm][fn][2];
        op[3 * (size_t)N_T] = acc[fm][fn][3];
      }
    }
  }
}

// out[i] = sum_s ws[s*OUT_ELEMS + i], vectorized float4, fixed order (deterministic)
template <int KSPLIT>
__global__ __launch_bounds__(256) void reduce_kernel(const float* __restrict__ ws,
                                                     float* __restrict__ out) {
  const int i4 = blockIdx.x * 256 + threadIdx.x;
  const size_t base = (size_t)i4 * 4;
  float4 a = *(const float4*)(ws + base);
#pragma unroll
  for (int s = 1; s < KSPLIT; ++s) {
    float4 b = *(const float4*)(ws + (size_t)s * OUT_ELEMS + base);
    a.x += b.x; a.y += b.y; a.z += b.z; a.w += b.w;
  }
  *(float4*)(out + base) = a;
}

extern "C" void kernel_launch(void* const* d_in, const int* in_sizes, int n_in,
                              void* d_out, int out_size, void* d_ws, size_t ws_size,
                              hipStream_t stream) {
  const float* x = (const float*)d_in[0];
  const int* qw = (const int*)d_in[1];
  const float* qr = (const float*)d_in[2];
  const float* qm = (const float*)d_in[3];
  float* out = (float*)d_out;
  float* ws = (float*)d_ws;

  constexpr int KS = 8;
  const size_t need = (size_t)KS * OUT_ELEMS * sizeof(float);
  if (ws_size >= need) {
    dim3 grid(N_T / BN, M_T / BM, KS);
    dq_gemm_kernel<KS, false><<<grid, dim3(256, 1, 1), 0, stream>>>(x, qw, qr, qm, ws);
    reduce_kernel<KS><<<OUT_ELEMS / 4 / 256, 256, 0, stream>>>(ws, out);
  } else {
    // fallback: known-good R2 path (KSPLIT=4, atomics into zeroed out)
    hipMemsetAsync(out, 0, (size_t)OUT_ELEMS * sizeof(float), stream);
    dim3 grid(N_T / BN, M_T / BM, 4);
    dq_gemm_kernel<4, true><<<grid, dim3(256, 1, 1), 0, stream>>>(x, qw, qr, qm, out);
  }
}

// Round 8
// 35.454 us; speedup vs baseline: 4.2969x; 1.4318x over previous
//
#include <hip/hip_runtime.h>
#include <hip/hip_bf16.h>

// InferenceLinear: out[m][n] = sum_k x[m][k] * (q[n][k]*qrange[n][k/256] + qmin[n][k/256])
// M=512, N=2048, K=4096, 16 groups of 256.
// R7 resubmit (infra failure, no signal). L3-BW theory: R2/R6 both ~52-57us with
// ~536MB of L2/L3 operand re-reads (64^2 tiles: A x32, B x8) = ~10 TB/s = Infinity
// Cache ceiling. Fix:
//  (1) 128x128 tiles (re-reads A x16, B x4 -> 268MB),
//  (2) XCD-aware remap: z=kc=XCD, so each XCD's k-slice working set (~5MB) is
//      L2-resident -> traffic served from L2 not L3.
// 512 threads (8 waves 2Mx4N, wave=64x32 via 4x2 16x16x32 frags), KSPLIT=8,
// ws partials + deterministic reduce.

#define M_T 512
#define N_T 2048
#define K_T 4096
#define NGRP 16
#define BM 128
#define BN 128
#define BK 64
#define OUT_ELEMS (M_T * N_T)

typedef __attribute__((ext_vector_type(8))) short mfrag_t;           // 8 bf16 (4 VGPR)
typedef __attribute__((ext_vector_type(8))) unsigned short u16x8;
typedef __attribute__((ext_vector_type(4))) float f32x4;

__device__ __forceinline__ unsigned short f2bf(float f) {
  union { __hip_bfloat16 h; unsigned short u; } c;
  c.h = __float2bfloat16(f);
  return c.u;
}

// XCDSWZ: decode 1D block id so that kc == XCD (b&7) and all 16 n-tiles of an
// (m, kc) panel land on the same XCD (assumes round-robin b%8 dispatch; wrong
// assumption only costs locality, not correctness).
// ATOMIC=false: write fp32 partial to ws slice; ATOMIC=true: atomicAdd into dst.
template <int KSPLIT, bool ATOMIC, bool XCDSWZ>
__global__ __launch_bounds__(512, 4) void dq_gemm_kernel(
    const float* __restrict__ x, const int* __restrict__ qw,
    const float* __restrict__ qrange, const float* __restrict__ qmin,
    float* __restrict__ dst) {
  constexpr int KC = K_T / KSPLIT;
  constexpr int NTC = KC / BK;

  // single-buffered, swizzled [row][slot^(row&7)] storage, 8-elem (16B) slots
  __shared__ __align__(16) unsigned short As[BM * BK];
  __shared__ __align__(16) unsigned short Bs[BN * BK];

  const int tid = threadIdx.x;
  int xt, yt, kc;
  if (XCDSWZ) {
    const int b = blockIdx.x;
    kc = b & 7;                 // XCD id == k-chunk
    const int slot = b >> 3;    // 0..63
    xt = slot & 15;             // n-tile
    yt = slot >> 4;             // m-tile (0..3)
  } else {
    const int b = blockIdx.x;
    xt = b & 15;
    yt = (b >> 4) & 3;
    kc = b >> 6;
  }
  const int n0 = xt * BN;
  const int m0 = yt * BM;
  const int kbase = kc * KC;

  // staging mapping: thread -> (row 0..127, 16-elem segment 0..3)
  const int srow = tid >> 2;
  const int sseg = tid & 3;

  const float* xp = x + (size_t)(m0 + srow) * K_T + kbase + sseg * 16;
  const int* qp = qw + (size_t)(n0 + srow) * K_T + kbase + sseg * 16;
  const float* qrp = qrange + (size_t)(n0 + srow) * NGRP;
  const float* qmp = qmin + (size_t)(n0 + srow) * NGRP;

  // compute mapping: 8 waves, 2(M) x 4(N); wave tile 64x32
  const int lane = tid & 63;
  const int wv = tid >> 6;
  const int wm = (wv >> 2) * 64;   // 0,64
  const int wn = (wv & 3) * 32;    // 0,32,64,96
  const int lr = lane & 15;
  const int lq = lane >> 4;

  float4 av[4];
  int4 qv[4];
  float sc, mn;

  // prologue loads (t=0)
  {
    const float* a = xp;
    av[0] = *(const float4*)(a + 0);
    av[1] = *(const float4*)(a + 4);
    av[2] = *(const float4*)(a + 8);
    av[3] = *(const float4*)(a + 12);
    const int4* q = (const int4*)qp;
    qv[0] = q[0]; qv[1] = q[1]; qv[2] = q[2]; qv[3] = q[3];
    sc = qrp[kc * (KC / 256)];
    mn = qmp[kc * (KC / 256)];
  }

  f32x4 acc[4][2] = {};

  const int rx7 = srow & 7;
  const int abase = srow * BK;
  const int wslot0 = ((sseg * 2) ^ rx7) << 3;
  const int wslot1 = ((sseg * 2 + 1) ^ rx7) << 3;
  const int rxl = lr & 7;  // read-side xor (row&7 == lr&7: wm,wn,f*16 mult of 8)

  for (int t = 0; t < NTC; ++t) {
    if (t > 0) __syncthreads();  // previous compute done before LDS overwrite

    // ---- stage regs -> LDS (convert to bf16 / dequant) ----
    {
      u16x8 pa0, pa1, pb0, pb1;
      pa0[0] = f2bf(av[0].x); pa0[1] = f2bf(av[0].y); pa0[2] = f2bf(av[0].z); pa0[3] = f2bf(av[0].w);
      pa0[4] = f2bf(av[1].x); pa0[5] = f2bf(av[1].y); pa0[6] = f2bf(av[1].z); pa0[7] = f2bf(av[1].w);
      pa1[0] = f2bf(av[2].x); pa1[1] = f2bf(av[2].y); pa1[2] = f2bf(av[2].z); pa1[3] = f2bf(av[2].w);
      pa1[4] = f2bf(av[3].x); pa1[5] = f2bf(av[3].y); pa1[6] = f2bf(av[3].z); pa1[7] = f2bf(av[3].w);
      pb0[0] = f2bf((float)qv[0].x * sc + mn); pb0[1] = f2bf((float)qv[0].y * sc + mn);
      pb0[2] = f2bf((float)qv[0].z * sc + mn); pb0[3] = f2bf((float)qv[0].w * sc + mn);
      pb0[4] = f2bf((float)qv[1].x * sc + mn); pb0[5] = f2bf((float)qv[1].y * sc + mn);
      pb0[6] = f2bf((float)qv[1].z * sc + mn); pb0[7] = f2bf((float)qv[1].w * sc + mn);
      pb1[0] = f2bf((float)qv[2].x * sc + mn); pb1[1] = f2bf((float)qv[2].y * sc + mn);
      pb1[2] = f2bf((float)qv[2].z * sc + mn); pb1[3] = f2bf((float)qv[2].w * sc + mn);
      pb1[4] = f2bf((float)qv[3].x * sc + mn); pb1[5] = f2bf((float)qv[3].y * sc + mn);
      pb1[6] = f2bf((float)qv[3].z * sc + mn); pb1[7] = f2bf((float)qv[3].w * sc + mn);
      *(u16x8*)&As[abase + wslot0] = pa0;
      *(u16x8*)&As[abase + wslot1] = pa1;
      *(u16x8*)&Bs[abase + wslot0] = pb0;
      *(u16x8*)&Bs[abase + wslot1] = pb1;
    }

    // ---- issue next tile's global loads (complete during compute phase) ----
    if (t + 1 < NTC) {
      const float* a = xp + (size_t)(t + 1) * BK;
      av[0] = *(const float4*)(a + 0);
      av[1] = *(const float4*)(a + 4);
      av[2] = *(const float4*)(a + 8);
      av[3] = *(const float4*)(a + 12);
      const int4* q = (const int4*)(qp + (size_t)(t + 1) * BK);
      qv[0] = q[0]; qv[1] = q[1]; qv[2] = q[2]; qv[3] = q[3];
      const int g = kc * (KC / 256) + ((t + 1) >> 2);  // group = 4 tiles of 64
      sc = qrp[g];
      mn = qmp[g];
    }

    __syncthreads();

    // ---- compute tile t: 2 K-substeps of 32; wave = 4x2 fragments ----
#pragma unroll
    for (int kk = 0; kk < 2; ++kk) {
      const int so = ((kk * 4 + lq) ^ rxl) << 3;
      mfrag_t af[4], bf[2];
#pragma unroll
      for (int fm = 0; fm < 4; ++fm)
        af[fm] = *(const mfrag_t*)&As[(wm + fm * 16 + lr) * BK + so];
#pragma unroll
      for (int fn = 0; fn < 2; ++fn)
        bf[fn] = *(const mfrag_t*)&Bs[(wn + fn * 16 + lr) * BK + so];
#pragma unroll
      for (int fm = 0; fm < 4; ++fm)
#pragma unroll
        for (int fn = 0; fn < 2; ++fn)
          acc[fm][fn] = __builtin_amdgcn_mfma_f32_16x16x32_bf16(af[fm], bf[fn], acc[fm][fn], 0, 0, 0);
    }
  }

  // ---- epilogue. C/D layout col=lane&15, row=(lane>>4)*4+reg ----
  float* base = ATOMIC ? dst : dst + (size_t)kc * OUT_ELEMS;
#pragma unroll
  for (int fm = 0; fm < 4; ++fm) {
#pragma unroll
    for (int fn = 0; fn < 2; ++fn) {
      const int r0 = m0 + wm + fm * 16 + lq * 4;
      const int c = n0 + wn + fn * 16 + lr;
      float* op = base + (size_t)r0 * N_T + c;
      if (ATOMIC) {
        atomicAdd(&op[0 * (size_t)N_T], acc[fm][fn][0]);
        atomicAdd(&op[1 * (size_t)N_T], acc[fm][fn][1]);
        atomicAdd(&op[2 * (size_t)N_T], acc[fm][fn][2]);
        atomicAdd(&op[3 * (size_t)N_T], acc[fm][fn][3]);
      } else {
        op[0 * (size_t)N_T] = acc[fm][fn][0];
        op[1 * (size_t)N_T] = acc[fm][fn][1];
        op[2 * (size_t)N_T] = acc[fm][fn][2];
        op[3 * (size_t)N_T] = acc[fm][fn][3];
      }
    }
  }
}

// out[i] = sum_s ws[s*OUT_ELEMS + i], vectorized float4, fixed order (deterministic)
template <int KSPLIT>
__global__ __launch_bounds__(256) void reduce_kernel(const float* __restrict__ ws,
                                                     float* __restrict__ out) {
  const int i4 = blockIdx.x * 256 + threadIdx.x;
  const size_t base = (size_t)i4 * 4;
  float4 a = *(const float4*)(ws + base);
#pragma unroll
  for (int s = 1; s < KSPLIT; ++s) {
    float4 b = *(const float4*)(ws + (size_t)s * OUT_ELEMS + base);
    a.x += b.x; a.y += b.y; a.z += b.z; a.w += b.w;
  }
  *(float4*)(out + base) = a;
}

extern "C" void kernel_launch(void* const* d_in, const int* in_sizes, int n_in,
                              void* d_out, int out_size, void* d_ws, size_t ws_size,
                              hipStream_t stream) {
  const float* x = (const float*)d_in[0];
  const int* qw = (const int*)d_in[1];
  const float* qr = (const float*)d_in[2];
  const float* qm = (const float*)d_in[3];
  float* out = (float*)d_out;
  float* ws = (float*)d_ws;

  constexpr int KS = 8;
  const size_t need = (size_t)KS * OUT_ELEMS * sizeof(float);
  if (ws_size >= need) {
    const int nblk = (N_T / BN) * (M_T / BM) * KS;  // 16*4*8 = 512
    dq_gemm_kernel<KS, false, true><<<nblk, dim3(512, 1, 1), 0, stream>>>(x, qw, qr, qm, ws);
    reduce_kernel<KS><<<OUT_ELEMS / 4 / 256, 256, 0, stream>>>(ws, out);
  } else {
    // fallback: KSPLIT=4, atomics into zeroed out, plain decode
    hipMemsetAsync(out, 0, (size_t)OUT_ELEMS * sizeof(float), stream);
    const int nblk = (N_T / BN) * (M_T / BM) * 4;
    dq_gemm_kernel<4, true, false><<<nblk, dim3(512, 1, 1), 0, stream>>>(x, qw, qr, qm, out);
  }
}